// Round 1
// baseline (606.940 us; speedup 1.0000x reference)
//
#include <hip/hip_runtime.h>
#include <hip/hip_bf16.h>
#include <stdint.h>

#define N_NODES 100000
#define E_EDGES 1600000
#define NEG_SLOPE 0.2f

typedef short short8 __attribute__((ext_vector_type(8)));
typedef float f32x4 __attribute__((ext_vector_type(4)));

__device__ __forceinline__ unsigned short f2bf(float f) {
  union { float f; unsigned int u; } c; c.f = f;
  unsigned int u = c.u;
  unsigned int r = u + 0x7FFFu + ((u >> 16) & 1u);
  return (unsigned short)(r >> 16);
}
__device__ __forceinline__ float bf2f(unsigned short b) {
  union { unsigned int u; float f; } c; c.u = ((unsigned int)b) << 16;
  return c.f;
}

// ---- detect int32 vs int64 edge_index: int64 => odd int32 words are all 0
__global__ void k_detect(const void* ei, int* flag) {
  int t = threadIdx.x;
  int v = ((const int*)ei)[2 * t + 1];
  unsigned long long b = __ballot(v != 0);
  if (t == 0) *flag = (b != 0ull) ? 1 : 0;  // 1 = int32 layout
}

// ---- pack W -> Bt[col][k] bf16, proj_w -> Pt[col][k] bf16, w3[h][d] = sum_o W_edge[h][d][o]*a3[h][o]
__global__ void k_prep(const float* __restrict__ W, const float* __restrict__ proj_w,
                       const float* __restrict__ W_edge, const float* __restrict__ att,
                       unsigned short* __restrict__ Bt, unsigned short* __restrict__ Pt,
                       float* __restrict__ w3) {
  int t = blockIdx.x * 256 + threadIdx.x;
  if (t < 65536) {
    int col = t >> 8, k = t & 255;
    int h = col >> 6, o = col & 63;
    Bt[t] = f2bf(W[h * 16384 + k * 64 + o]);
  } else if (t < 131072) {
    int t2 = t - 65536;
    int o = t2 >> 8, i = t2 & 255;
    Pt[t2] = f2bf(proj_w[i * 256 + o]);
  } else if (t < 131136) {
    int t3 = t - 131072;
    int h = t3 >> 4, d = t3 & 15;
    float s = 0.f;
    for (int o = 0; o < 64; ++o)
      s += W_edge[h * 1024 + d * 64 + o] * att[h * 192 + 128 + o];
    w3[t3] = s;
  }
}

// ---- GEMM: xwb[n][h*64+o] = bf16( sum_k x[n][k] * Bt[h*64+o][k] )
__global__ __launch_bounds__(256) void k_gemm_x(const float* __restrict__ x,
    const unsigned short* __restrict__ Bt, unsigned short* __restrict__ xwb) {
  const int bm = blockIdx.x * 64;
  const int wave = threadIdx.x >> 6;
  const int lane = threadIdx.x & 63;
  const int l16 = lane & 15, lg = lane >> 4;
  const int colbase = wave * 64;
  f32x4 acc[4][4];
#pragma unroll
  for (int i = 0; i < 4; i++)
#pragma unroll
    for (int j = 0; j < 4; j++) acc[i][j] = (f32x4){0.f, 0.f, 0.f, 0.f};

  for (int ks = 0; ks < 8; ++ks) {
    const int k0 = ks * 32 + lg * 8;
    short8 a[4], b[4];
#pragma unroll
    for (int mi = 0; mi < 4; mi++) {
      int row = bm + mi * 16 + l16;
      if (row < N_NODES) {
        const float* p = x + (size_t)row * 256 + k0;
        float4 v0 = *(const float4*)(p);
        float4 v1 = *(const float4*)(p + 4);
        a[mi][0] = (short)f2bf(v0.x); a[mi][1] = (short)f2bf(v0.y);
        a[mi][2] = (short)f2bf(v0.z); a[mi][3] = (short)f2bf(v0.w);
        a[mi][4] = (short)f2bf(v1.x); a[mi][5] = (short)f2bf(v1.y);
        a[mi][6] = (short)f2bf(v1.z); a[mi][7] = (short)f2bf(v1.w);
      } else {
        a[mi] = (short8){0, 0, 0, 0, 0, 0, 0, 0};
      }
    }
#pragma unroll
    for (int ni = 0; ni < 4; ni++) {
      int col = colbase + ni * 16 + l16;
      b[ni] = *(const short8*)(Bt + col * 256 + k0);
    }
#pragma unroll
    for (int mi = 0; mi < 4; mi++)
#pragma unroll
      for (int ni = 0; ni < 4; ni++)
        acc[mi][ni] = __builtin_amdgcn_mfma_f32_16x16x32_bf16(a[mi], b[ni], acc[mi][ni], 0, 0, 0);
  }
#pragma unroll
  for (int mi = 0; mi < 4; mi++) {
#pragma unroll
    for (int r = 0; r < 4; r++) {
      int row = bm + mi * 16 + lg * 4 + r;
      if (row < N_NODES) {
#pragma unroll
        for (int ni = 0; ni < 4; ni++) {
          int col = colbase + ni * 16 + l16;
          xwb[(size_t)row * 256 + col] = f2bf(acc[mi][ni][r]);
        }
      }
    }
  }
}

// ---- s1[n][h] = dot(xw[n][h], a1[h]); s2 with a2
__global__ void k_scores(const unsigned short* __restrict__ xwb, const float* __restrict__ att,
                         float* __restrict__ s1, float* __restrict__ s2) {
  int t = blockIdx.x * 256 + threadIdx.x;
  if (t >= N_NODES * 4) return;
  int n = t >> 2, h = t & 3;
  const unsigned short* row = xwb + (size_t)n * 256 + h * 64;
  const float* a1 = att + h * 192;
  const float* a2 = a1 + 64;
  float d1 = 0.f, d2 = 0.f;
#pragma unroll
  for (int i = 0; i < 8; ++i) {
    short8 v = *(const short8*)(row + i * 8);
#pragma unroll
    for (int j = 0; j < 8; ++j) {
      float f = bf2f((unsigned short)v[j]);
      d1 += f * a1[i * 8 + j];
      d2 += f * a2[i * 8 + j];
    }
  }
  s1[t] = d1;
  s2[t] = d2;
}

__global__ void k_deg(const void* ei, const int* __restrict__ flag, int* __restrict__ deg) {
  int e = blockIdx.x * 256 + threadIdx.x;
  if (e >= E_EDGES) return;
  int f = *flag;
  int dst = f ? ((const int*)ei)[E_EDGES + e] : (int)(((const long long*)ei)[E_EDGES + e]);
  atomicAdd(&deg[dst], 1);
}

__global__ void k_scan1(const int* __restrict__ deg, int* __restrict__ rowptr, int* __restrict__ bsum) {
  __shared__ int s[256];
  int t = threadIdx.x;
  int i = blockIdx.x * 256 + t;
  int orig = (i < N_NODES) ? deg[i] : 0;
  int v = orig;
  s[t] = v;
  __syncthreads();
  for (int off = 1; off < 256; off <<= 1) {
    int x = (t >= off) ? s[t - off] : 0;
    __syncthreads();
    v += x;
    s[t] = v;
    __syncthreads();
  }
  if (i < N_NODES) rowptr[i] = v - orig;  // block-local exclusive
  if (t == 255) bsum[blockIdx.x] = v;     // block total
}

__global__ void k_scan2(int* __restrict__ bsum, int nb) {
  __shared__ int s[512];
  int t = threadIdx.x;
  int v = (t < nb) ? bsum[t] : 0;
  int incl = v;
  s[t] = v;
  __syncthreads();
  for (int off = 1; off < 512; off <<= 1) {
    int x = (t >= off) ? s[t - off] : 0;
    __syncthreads();
    incl += x;
    s[t] = incl;
    __syncthreads();
  }
  if (t < nb) bsum[t] = incl - v;  // exclusive
}

__global__ void k_scan3(int* __restrict__ rowptr, const int* __restrict__ bsum, int* __restrict__ cursor) {
  int i = blockIdx.x * 256 + threadIdx.x;
  if (i < N_NODES) {
    int v = rowptr[i] + bsum[i >> 8];
    rowptr[i] = v;
    cursor[i] = v;
  }
  if (i == 0) rowptr[N_NODES] = E_EDGES;
}

// ---- per-edge: e-vals (4 heads), leakyrelu, exp (no max shift needed: softmax is shift-invariant),
//      scatter exp + src into CSR slot
__global__ void k_edge(const void* ei, const int* __restrict__ flag,
                       const float* __restrict__ edge_attr,
                       const float* __restrict__ s1, const float* __restrict__ s2,
                       const float* __restrict__ w3g, int* __restrict__ cursor,
                       int* __restrict__ src_csr, float4* __restrict__ exp_csr) {
  __shared__ float w3[64];
  if (threadIdx.x < 64) w3[threadIdx.x] = w3g[threadIdx.x];
  __syncthreads();
  int e = blockIdx.x * 256 + threadIdx.x;
  if (e >= E_EDGES) return;
  int f = *flag;
  int src, dst;
  if (f) {
    src = ((const int*)ei)[e];
    dst = ((const int*)ei)[E_EDGES + e];
  } else {
    src = (int)(((const long long*)ei)[e]);
    dst = (int)(((const long long*)ei)[E_EDGES + e]);
  }
  float4 sd = *(const float4*)(s1 + (size_t)dst * 4);
  float4 ss = *(const float4*)(s2 + (size_t)src * 4);
  float ea[16];
#pragma unroll
  for (int i = 0; i < 4; i++) {
    float4 v = *(const float4*)(edge_attr + (size_t)e * 16 + i * 4);
    ea[4 * i] = v.x; ea[4 * i + 1] = v.y; ea[4 * i + 2] = v.z; ea[4 * i + 3] = v.w;
  }
  float ex[4];
#pragma unroll
  for (int h = 0; h < 4; h++) {
    float d = 0.f;
#pragma unroll
    for (int i = 0; i < 16; i++) d += ea[i] * w3[h * 16 + i];
    float v = (&sd.x)[h] + (&ss.x)[h] + d;
    v = (v >= 0.f) ? v : NEG_SLOPE * v;
    ex[h] = __expf(v);
  }
  int p = atomicAdd(&cursor[dst], 1);
  src_csr[p] = src;
  exp_csr[p] = make_float4(ex[0], ex[1], ex[2], ex[3]);
}

// ---- one wave per node: out_h[n][c] = (1/den) * sum_edges exp * xw[src][c]; write bf16
__global__ __launch_bounds__(256) void k_aggr(const int* __restrict__ rowptr,
    const int* __restrict__ src_csr, const float4* __restrict__ exp_csr,
    const unsigned short* __restrict__ xwb, unsigned short* __restrict__ out_hb) {
  int n = blockIdx.x * 4 + (threadIdx.x >> 6);
  if (n >= N_NODES) return;
  int lane = threadIdx.x & 63;
  int beg = rowptr[n], end = rowptr[n + 1];
  float accA0 = 0.f, accA1 = 0.f, accB0 = 0.f, accB1 = 0.f;
  float den0 = 0.f, den1 = 0.f, den2 = 0.f, den3 = 0.f;
  const int cA = 2 * lane;        // dims 0..127  (heads 0,1)
  const int cB = 128 + 2 * lane;  // dims 128..255 (heads 2,3)
  for (int i = beg; i < end; ++i) {
    int s = src_csr[i];
    float4 ex = exp_csr[i];
    den0 += ex.x; den1 += ex.y; den2 += ex.z; den3 += ex.w;
    const unsigned short* row = xwb + (size_t)s * 256;
    unsigned int uA = *(const unsigned int*)(row + cA);
    unsigned int uB = *(const unsigned int*)(row + cB);
    float wAB = (lane < 32) ? ex.x : ex.y;
    float wCD = (lane < 32) ? ex.z : ex.w;
    accA0 += wAB * bf2f((unsigned short)(uA & 0xFFFFu));
    accA1 += wAB * bf2f((unsigned short)(uA >> 16));
    accB0 += wCD * bf2f((unsigned short)(uB & 0xFFFFu));
    accB1 += wCD * bf2f((unsigned short)(uB >> 16));
  }
  float dA = ((lane < 32) ? den0 : den1) + 1e-16f;
  float dB = ((lane < 32) ? den2 : den3) + 1e-16f;
  unsigned int oA = ((unsigned int)f2bf(accA1 / dA) << 16) | (unsigned int)f2bf(accA0 / dA);
  unsigned int oB = ((unsigned int)f2bf(accB1 / dB) << 16) | (unsigned int)f2bf(accB0 / dB);
  *(unsigned int*)(out_hb + (size_t)n * 256 + cA) = oA;
  *(unsigned int*)(out_hb + (size_t)n * 256 + cB) = oB;
}

// ---- out = elu(out_hb @ Pt^T + bias)
__global__ __launch_bounds__(256) void k_gemm_out(const unsigned short* __restrict__ A,
    const unsigned short* __restrict__ Pt, const float* __restrict__ bias,
    float* __restrict__ out) {
  const int bm = blockIdx.x * 64;
  const int wave = threadIdx.x >> 6;
  const int lane = threadIdx.x & 63;
  const int l16 = lane & 15, lg = lane >> 4;
  const int colbase = wave * 64;
  f32x4 acc[4][4];
#pragma unroll
  for (int i = 0; i < 4; i++)
#pragma unroll
    for (int j = 0; j < 4; j++) acc[i][j] = (f32x4){0.f, 0.f, 0.f, 0.f};

  for (int ks = 0; ks < 8; ++ks) {
    const int k0 = ks * 32 + lg * 8;
    short8 a[4], b[4];
#pragma unroll
    for (int mi = 0; mi < 4; mi++) {
      int row = bm + mi * 16 + l16;
      if (row < N_NODES) {
        a[mi] = *(const short8*)(A + (size_t)row * 256 + k0);
      } else {
        a[mi] = (short8){0, 0, 0, 0, 0, 0, 0, 0};
      }
    }
#pragma unroll
    for (int ni = 0; ni < 4; ni++) {
      int col = colbase + ni * 16 + l16;
      b[ni] = *(const short8*)(Pt + col * 256 + k0);
    }
#pragma unroll
    for (int mi = 0; mi < 4; mi++)
#pragma unroll
      for (int ni = 0; ni < 4; ni++)
        acc[mi][ni] = __builtin_amdgcn_mfma_f32_16x16x32_bf16(a[mi], b[ni], acc[mi][ni], 0, 0, 0);
  }
#pragma unroll
  for (int mi = 0; mi < 4; mi++) {
#pragma unroll
    for (int r = 0; r < 4; r++) {
      int row = bm + mi * 16 + lg * 4 + r;
      if (row < N_NODES) {
#pragma unroll
        for (int ni = 0; ni < 4; ni++) {
          int col = colbase + ni * 16 + l16;
          float v = acc[mi][ni][r] + bias[col];
          v = (v > 0.f) ? v : expm1f(v);
          out[(size_t)row * 256 + col] = v;
        }
      }
    }
  }
}

extern "C" void kernel_launch(void* const* d_in, const int* in_sizes, int n_in,
                              void* d_out, int out_size, void* d_ws, size_t ws_size,
                              hipStream_t stream) {
  const float* x = (const float*)d_in[0];
  const void* ei = d_in[1];
  const float* edge_attr = (const float*)d_in[2];
  const float* W = (const float*)d_in[3];
  const float* W_edge = (const float*)d_in[4];
  const float* att = (const float*)d_in[5];
  const float* proj_w = (const float*)d_in[6];
  const float* proj_b = (const float*)d_in[7];
  float* out = (float*)d_out;

  char* ws = (char*)d_ws;
  size_t off = 0;
  auto alloc = [&](size_t bytes) -> void* {
    void* p = (void*)(ws + off);
    off += (bytes + 255) & ~(size_t)255;
    return p;
  };
  unsigned short* xwb   = (unsigned short*)alloc((size_t)N_NODES * 256 * 2);
  unsigned short* outhb = (unsigned short*)alloc((size_t)N_NODES * 256 * 2);
  float* s1      = (float*)alloc((size_t)N_NODES * 4 * 4);
  float* s2      = (float*)alloc((size_t)N_NODES * 4 * 4);
  int* deg       = (int*)alloc((size_t)N_NODES * 4);
  int* rowptr    = (int*)alloc((size_t)(N_NODES + 1) * 4);
  int* cursor    = (int*)alloc((size_t)N_NODES * 4);
  int* bsum      = (int*)alloc(512 * 4);
  int* src_csr   = (int*)alloc((size_t)E_EDGES * 4);
  float4* exp_csr = (float4*)alloc((size_t)E_EDGES * 16);
  unsigned short* Bt = (unsigned short*)alloc(65536 * 2);
  unsigned short* Pt = (unsigned short*)alloc(65536 * 2);
  float* w3      = (float*)alloc(64 * 4);
  int* flag      = (int*)alloc(256);

  const int NB_SCAN = (N_NODES + 255) / 256;  // 391

  hipMemsetAsync(deg, 0, (size_t)N_NODES * 4, stream);
  k_detect<<<1, 64, 0, stream>>>(ei, flag);
  k_prep<<<(131136 + 255) / 256, 256, 0, stream>>>(W, proj_w, W_edge, att, Bt, Pt, w3);
  k_gemm_x<<<(N_NODES + 63) / 64, 256, 0, stream>>>(x, Bt, xwb);
  k_scores<<<(N_NODES * 4 + 255) / 256, 256, 0, stream>>>(xwb, att, s1, s2);
  k_deg<<<(E_EDGES + 255) / 256, 256, 0, stream>>>(ei, flag, deg);
  k_scan1<<<NB_SCAN, 256, 0, stream>>>(deg, rowptr, bsum);
  k_scan2<<<1, 512, 0, stream>>>(bsum, NB_SCAN);
  k_scan3<<<NB_SCAN, 256, 0, stream>>>(rowptr, bsum, cursor);
  k_edge<<<(E_EDGES + 255) / 256, 256, 0, stream>>>(ei, flag, edge_attr, s1, s2, w3,
                                                    cursor, src_csr, exp_csr);
  k_aggr<<<(N_NODES + 3) / 4, 256, 0, stream>>>(rowptr, src_csr, exp_csr, xwb, outhb);
  k_gemm_out<<<(N_NODES + 63) / 64, 256, 0, stream>>>(outhb, Pt, proj_b, out);
}

// Round 2
// 550.279 us; speedup vs baseline: 1.1030x; 1.1030x over previous
//
#include <hip/hip_runtime.h>
#include <hip/hip_bf16.h>
#include <stdint.h>

#define N_NODES 100000
#define E_EDGES 1600000
#define NEG_SLOPE 0.2f

typedef short short8 __attribute__((ext_vector_type(8)));
typedef float f32x4 __attribute__((ext_vector_type(4)));

__device__ __forceinline__ unsigned short f2bf(float f) {
  union { float f; unsigned int u; } c; c.f = f;
  unsigned int u = c.u;
  unsigned int r = u + 0x7FFFu + ((u >> 16) & 1u);
  return (unsigned short)(r >> 16);
}
__device__ __forceinline__ float asf(unsigned int u) {
  union { unsigned int u; float f; } c; c.u = u;
  return c.f;
}
__device__ __forceinline__ float bf2f(unsigned short b) { return asf(((unsigned int)b) << 16); }

// ---- detect int32 vs int64 edge_index: int64 => odd int32 words are all 0
__global__ void k_detect(const void* ei, int* flag) {
  int t = threadIdx.x;
  int v = ((const int*)ei)[2 * t + 1];
  unsigned long long b = __ballot(v != 0);
  if (t == 0) *flag = (b != 0ull) ? 1 : 0;  // 1 = int32 layout
}

// ---- pack W -> Bt[col][k] bf16, proj_w -> Pt[col][k] bf16, w3[h][d] = sum_o W_edge[h][d][o]*a3[h][o]
__global__ void k_prep(const float* __restrict__ W, const float* __restrict__ proj_w,
                       const float* __restrict__ W_edge, const float* __restrict__ att,
                       unsigned short* __restrict__ Bt, unsigned short* __restrict__ Pt,
                       float* __restrict__ w3) {
  int t = blockIdx.x * 256 + threadIdx.x;
  if (t < 65536) {
    int col = t >> 8, k = t & 255;
    int h = col >> 6, o = col & 63;
    Bt[t] = f2bf(W[h * 16384 + k * 64 + o]);
  } else if (t < 131072) {
    int t2 = t - 65536;
    int o = t2 >> 8, i = t2 & 255;
    Pt[t2] = f2bf(proj_w[i * 256 + o]);
  } else if (t < 131136) {
    int t3 = t - 131072;
    int h = t3 >> 4, d = t3 & 15;
    float s = 0.f;
    for (int o = 0; o < 64; ++o)
      s += W_edge[h * 1024 + d * 64 + o] * att[h * 192 + 128 + o];
    w3[t3] = s;
  }
}

// ---- GEMM: xwb[n][h*64+o] = bf16( sum_k x[n][k] * Bt[h*64+o][k] )
//      fused epilogue: s1[n][h] = dot(xw[n][h], a1[h]); s2 with a2   (wave w == head w)
__global__ __launch_bounds__(256) void k_gemm_x(const float* __restrict__ x,
    const unsigned short* __restrict__ Bt, const float* __restrict__ att,
    unsigned short* __restrict__ xwb, float* __restrict__ s1, float* __restrict__ s2) {
  const int bm = blockIdx.x * 64;
  const int wave = threadIdx.x >> 6;
  const int lane = threadIdx.x & 63;
  const int l16 = lane & 15, lg = lane >> 4;
  const int colbase = wave * 64;
  f32x4 acc[4][4];
#pragma unroll
  for (int i = 0; i < 4; i++)
#pragma unroll
    for (int j = 0; j < 4; j++) acc[i][j] = (f32x4){0.f, 0.f, 0.f, 0.f};

  for (int ks = 0; ks < 8; ++ks) {
    const int k0 = ks * 32 + lg * 8;
    short8 a[4], b[4];
#pragma unroll
    for (int mi = 0; mi < 4; mi++) {
      int row = bm + mi * 16 + l16;
      if (row < N_NODES) {
        const float* p = x + (size_t)row * 256 + k0;
        float4 v0 = *(const float4*)(p);
        float4 v1 = *(const float4*)(p + 4);
        a[mi][0] = (short)f2bf(v0.x); a[mi][1] = (short)f2bf(v0.y);
        a[mi][2] = (short)f2bf(v0.z); a[mi][3] = (short)f2bf(v0.w);
        a[mi][4] = (short)f2bf(v1.x); a[mi][5] = (short)f2bf(v1.y);
        a[mi][6] = (short)f2bf(v1.z); a[mi][7] = (short)f2bf(v1.w);
      } else {
        a[mi] = (short8){0, 0, 0, 0, 0, 0, 0, 0};
      }
    }
#pragma unroll
    for (int ni = 0; ni < 4; ni++) {
      int col = colbase + ni * 16 + l16;
      b[ni] = *(const short8*)(Bt + col * 256 + k0);
    }
#pragma unroll
    for (int mi = 0; mi < 4; mi++)
#pragma unroll
      for (int ni = 0; ni < 4; ni++)
        acc[mi][ni] = __builtin_amdgcn_mfma_f32_16x16x32_bf16(a[mi], b[ni], acc[mi][ni], 0, 0, 0);
  }

  // epilogue: store xwb + fused per-row attention scores for this wave's head
  float a1v[4], a2v[4];
#pragma unroll
  for (int ni = 0; ni < 4; ni++) {
    a1v[ni] = att[wave * 192 + ni * 16 + l16];
    a2v[ni] = att[wave * 192 + 64 + ni * 16 + l16];
  }
#pragma unroll
  for (int mi = 0; mi < 4; mi++) {
#pragma unroll
    for (int r = 0; r < 4; r++) {
      int row = bm + mi * 16 + lg * 4 + r;
      float p1 = 0.f, p2 = 0.f;
#pragma unroll
      for (int ni = 0; ni < 4; ni++) {
        float v = acc[mi][ni][r];
        p1 += v * a1v[ni];
        p2 += v * a2v[ni];
      }
#pragma unroll
      for (int m = 1; m < 16; m <<= 1) {
        p1 += __shfl_xor(p1, m, 64);
        p2 += __shfl_xor(p2, m, 64);
      }
      if (row < N_NODES) {
#pragma unroll
        for (int ni = 0; ni < 4; ni++) {
          int col = colbase + ni * 16 + l16;
          xwb[(size_t)row * 256 + col] = f2bf(acc[mi][ni][r]);
        }
        if (l16 == 0) {
          s1[row * 4 + wave] = p1;
          s2[row * 4 + wave] = p2;
        }
      }
    }
  }
}

__global__ void k_deg(const void* ei, const int* __restrict__ flag, int* __restrict__ deg) {
  int e = blockIdx.x * 256 + threadIdx.x;
  if (e >= E_EDGES) return;
  int f = *flag;
  int dst = f ? ((const int*)ei)[E_EDGES + e] : (int)(((const long long*)ei)[E_EDGES + e]);
  atomicAdd(&deg[dst], 1);
}

__global__ void k_scan1(const int* __restrict__ deg, int* __restrict__ rowptr, int* __restrict__ bsum) {
  __shared__ int s[256];
  int t = threadIdx.x;
  int i = blockIdx.x * 256 + t;
  int orig = (i < N_NODES) ? deg[i] : 0;
  int v = orig;
  s[t] = v;
  __syncthreads();
  for (int off = 1; off < 256; off <<= 1) {
    int x = (t >= off) ? s[t - off] : 0;
    __syncthreads();
    v += x;
    s[t] = v;
    __syncthreads();
  }
  if (i < N_NODES) rowptr[i] = v - orig;  // block-local exclusive
  if (t == 255) bsum[blockIdx.x] = v;     // block total
}

__global__ void k_scan2(int* __restrict__ bsum, int nb) {
  __shared__ int s[512];
  int t = threadIdx.x;
  int v = (t < nb) ? bsum[t] : 0;
  int incl = v;
  s[t] = v;
  __syncthreads();
  for (int off = 1; off < 512; off <<= 1) {
    int x = (t >= off) ? s[t - off] : 0;
    __syncthreads();
    incl += x;
    s[t] = incl;
    __syncthreads();
  }
  if (t < nb) bsum[t] = incl - v;  // exclusive
}

__global__ void k_scan3(int* __restrict__ rowptr, const int* __restrict__ bsum, int* __restrict__ cursor) {
  int i = blockIdx.x * 256 + threadIdx.x;
  if (i < N_NODES) {
    int v = rowptr[i] + bsum[i >> 8];
    rowptr[i] = v;
    cursor[i] = v;
  }
  if (i == 0) rowptr[N_NODES] = E_EDGES;
}

// ---- per-edge: e-vals (4 heads), leakyrelu, exp (softmax is shift-invariant -> no max pass),
//      scatter (src, exp packed bf16) into CSR slot
__global__ void k_edge(const void* ei, const int* __restrict__ flag,
                       const float* __restrict__ edge_attr,
                       const float* __restrict__ s1, const float* __restrict__ s2,
                       const float* __restrict__ w3g, int* __restrict__ cursor,
                       int* __restrict__ src_csr, uint2* __restrict__ expb) {
  __shared__ float w3[64];
  if (threadIdx.x < 64) w3[threadIdx.x] = w3g[threadIdx.x];
  __syncthreads();
  int e = blockIdx.x * 256 + threadIdx.x;
  if (e >= E_EDGES) return;
  int f = *flag;
  int src, dst;
  if (f) {
    src = ((const int*)ei)[e];
    dst = ((const int*)ei)[E_EDGES + e];
  } else {
    src = (int)(((const long long*)ei)[e]);
    dst = (int)(((const long long*)ei)[E_EDGES + e]);
  }
  float4 sd = *(const float4*)(s1 + (size_t)dst * 4);
  float4 ss = *(const float4*)(s2 + (size_t)src * 4);
  float ea[16];
#pragma unroll
  for (int i = 0; i < 4; i++) {
    float4 v = *(const float4*)(edge_attr + (size_t)e * 16 + i * 4);
    ea[4 * i] = v.x; ea[4 * i + 1] = v.y; ea[4 * i + 2] = v.z; ea[4 * i + 3] = v.w;
  }
  float ex[4];
#pragma unroll
  for (int h = 0; h < 4; h++) {
    float d = 0.f;
#pragma unroll
    for (int i = 0; i < 16; i++) d += ea[i] * w3[h * 16 + i];
    float v = (&sd.x)[h] + (&ss.x)[h] + d;
    v = (v >= 0.f) ? v : NEG_SLOPE * v;
    ex[h] = __expf(v);
  }
  unsigned int p0 = ((unsigned int)f2bf(ex[1]) << 16) | (unsigned int)f2bf(ex[0]);
  unsigned int p1 = ((unsigned int)f2bf(ex[3]) << 16) | (unsigned int)f2bf(ex[2]);
  int p = atomicAdd(&cursor[dst], 1);
  src_csr[p] = src;
  expb[p] = make_uint2(p0, p1);
}

// ---- one wave per node: out_h[n][c] = (1/den) * sum_edges exp * xw[src][c]; write bf16
//      unroll x4: 8 outstanding gathers, src hoisted to SGPR (wave-uniform)
__global__ __launch_bounds__(256) void k_aggr(const int* __restrict__ rowptr,
    const int* __restrict__ src_csr, const uint2* __restrict__ expb,
    const unsigned short* __restrict__ xwb, unsigned short* __restrict__ out_hb) {
  int n = blockIdx.x * 4 + (threadIdx.x >> 6);
  if (n >= N_NODES) return;
  int lane = threadIdx.x & 63;
  int beg = rowptr[n], end = rowptr[n + 1];
  const int cA = 2 * lane;  // dims cA, cA+1 (A-half: heads 0/1), +128: B-half (heads 2/3)
  const bool lo32 = (lane < 32);
  float accA0 = 0.f, accA1 = 0.f, accB0 = 0.f, accB1 = 0.f;
  float den0 = 0.f, den1 = 0.f, den2 = 0.f, den3 = 0.f;

#define EDGE_FMA(eu, uA, uB)                                              \
  {                                                                       \
    float d0 = asf(eu.x << 16), d1 = asf(eu.x & 0xFFFF0000u);             \
    float d2 = asf(eu.y << 16), d3 = asf(eu.y & 0xFFFF0000u);             \
    den0 += d0; den1 += d1; den2 += d2; den3 += d3;                       \
    float wAB = lo32 ? d0 : d1;                                           \
    float wCD = lo32 ? d2 : d3;                                           \
    accA0 += wAB * asf(uA << 16); accA1 += wAB * asf(uA & 0xFFFF0000u);   \
    accB0 += wCD * asf(uB << 16); accB1 += wCD * asf(uB & 0xFFFF0000u);   \
  }

  int i = beg;
  for (; i + 4 <= end; i += 4) {
    int s0 = __builtin_amdgcn_readfirstlane(src_csr[i]);
    int s1_ = __builtin_amdgcn_readfirstlane(src_csr[i + 1]);
    int s2_ = __builtin_amdgcn_readfirstlane(src_csr[i + 2]);
    int s3_ = __builtin_amdgcn_readfirstlane(src_csr[i + 3]);
    uint2 e0 = expb[i], e1 = expb[i + 1], e2 = expb[i + 2], e3 = expb[i + 3];
    const unsigned short* r0 = xwb + (size_t)s0 * 256;
    const unsigned short* r1 = xwb + (size_t)s1_ * 256;
    const unsigned short* r2 = xwb + (size_t)s2_ * 256;
    const unsigned short* r3 = xwb + (size_t)s3_ * 256;
    unsigned int uA0 = *(const unsigned int*)(r0 + cA);
    unsigned int uB0 = *(const unsigned int*)(r0 + cA + 128);
    unsigned int uA1 = *(const unsigned int*)(r1 + cA);
    unsigned int uB1 = *(const unsigned int*)(r1 + cA + 128);
    unsigned int uA2 = *(const unsigned int*)(r2 + cA);
    unsigned int uB2 = *(const unsigned int*)(r2 + cA + 128);
    unsigned int uA3 = *(const unsigned int*)(r3 + cA);
    unsigned int uB3 = *(const unsigned int*)(r3 + cA + 128);
    EDGE_FMA(e0, uA0, uB0);
    EDGE_FMA(e1, uA1, uB1);
    EDGE_FMA(e2, uA2, uB2);
    EDGE_FMA(e3, uA3, uB3);
  }
  for (; i < end; ++i) {
    int s0 = __builtin_amdgcn_readfirstlane(src_csr[i]);
    uint2 e0 = expb[i];
    const unsigned short* r0 = xwb + (size_t)s0 * 256;
    unsigned int uA0 = *(const unsigned int*)(r0 + cA);
    unsigned int uB0 = *(const unsigned int*)(r0 + cA + 128);
    EDGE_FMA(e0, uA0, uB0);
  }
#undef EDGE_FMA

  float dA = (lo32 ? den0 : den1) + 1e-16f;
  float dB = (lo32 ? den2 : den3) + 1e-16f;
  unsigned int oA = ((unsigned int)f2bf(accA1 / dA) << 16) | (unsigned int)f2bf(accA0 / dA);
  unsigned int oB = ((unsigned int)f2bf(accB1 / dB) << 16) | (unsigned int)f2bf(accB0 / dB);
  *(unsigned int*)(out_hb + (size_t)n * 256 + cA) = oA;
  *(unsigned int*)(out_hb + (size_t)n * 256 + cA + 128) = oB;
}

// ---- out = elu(out_hb @ Pt^T + bias)
__global__ __launch_bounds__(256) void k_gemm_out(const unsigned short* __restrict__ A,
    const unsigned short* __restrict__ Pt, const float* __restrict__ bias,
    float* __restrict__ out) {
  const int bm = blockIdx.x * 64;
  const int wave = threadIdx.x >> 6;
  const int lane = threadIdx.x & 63;
  const int l16 = lane & 15, lg = lane >> 4;
  const int colbase = wave * 64;
  f32x4 acc[4][4];
#pragma unroll
  for (int i = 0; i < 4; i++)
#pragma unroll
    for (int j = 0; j < 4; j++) acc[i][j] = (f32x4){0.f, 0.f, 0.f, 0.f};

  for (int ks = 0; ks < 8; ++ks) {
    const int k0 = ks * 32 + lg * 8;
    short8 a[4], b[4];
#pragma unroll
    for (int mi = 0; mi < 4; mi++) {
      int row = bm + mi * 16 + l16;
      if (row < N_NODES) {
        a[mi] = *(const short8*)(A + (size_t)row * 256 + k0);
      } else {
        a[mi] = (short8){0, 0, 0, 0, 0, 0, 0, 0};
      }
    }
#pragma unroll
    for (int ni = 0; ni < 4; ni++) {
      int col = colbase + ni * 16 + l16;
      b[ni] = *(const short8*)(Pt + col * 256 + k0);
    }
#pragma unroll
    for (int mi = 0; mi < 4; mi++)
#pragma unroll
      for (int ni = 0; ni < 4; ni++)
        acc[mi][ni] = __builtin_amdgcn_mfma_f32_16x16x32_bf16(a[mi], b[ni], acc[mi][ni], 0, 0, 0);
  }
#pragma unroll
  for (int mi = 0; mi < 4; mi++) {
#pragma unroll
    for (int r = 0; r < 4; r++) {
      int row = bm + mi * 16 + lg * 4 + r;
      if (row < N_NODES) {
#pragma unroll
        for (int ni = 0; ni < 4; ni++) {
          int col = colbase + ni * 16 + l16;
          float v = acc[mi][ni][r] + bias[col];
          v = (v > 0.f) ? v : expm1f(v);
          out[(size_t)row * 256 + col] = v;
        }
      }
    }
  }
}

extern "C" void kernel_launch(void* const* d_in, const int* in_sizes, int n_in,
                              void* d_out, int out_size, void* d_ws, size_t ws_size,
                              hipStream_t stream) {
  const float* x = (const float*)d_in[0];
  const void* ei = d_in[1];
  const float* edge_attr = (const float*)d_in[2];
  const float* W = (const float*)d_in[3];
  const float* W_edge = (const float*)d_in[4];
  const float* att = (const float*)d_in[5];
  const float* proj_w = (const float*)d_in[6];
  const float* proj_b = (const float*)d_in[7];
  float* out = (float*)d_out;

  char* ws = (char*)d_ws;
  size_t off = 0;
  auto alloc = [&](size_t bytes) -> void* {
    void* p = (void*)(ws + off);
    off += (bytes + 255) & ~(size_t)255;
    return p;
  };
  unsigned short* xwb   = (unsigned short*)alloc((size_t)N_NODES * 256 * 2);
  unsigned short* outhb = (unsigned short*)alloc((size_t)N_NODES * 256 * 2);
  float* s1      = (float*)alloc((size_t)N_NODES * 4 * 4);
  float* s2      = (float*)alloc((size_t)N_NODES * 4 * 4);
  int* deg       = (int*)alloc((size_t)N_NODES * 4);
  int* rowptr    = (int*)alloc((size_t)(N_NODES + 1) * 4);
  int* cursor    = (int*)alloc((size_t)N_NODES * 4);
  int* bsum      = (int*)alloc(512 * 4);
  int* src_csr   = (int*)alloc((size_t)E_EDGES * 4);
  uint2* expb    = (uint2*)alloc((size_t)E_EDGES * 8);
  unsigned short* Bt = (unsigned short*)alloc(65536 * 2);
  unsigned short* Pt = (unsigned short*)alloc(65536 * 2);
  float* w3      = (float*)alloc(64 * 4);
  int* flag      = (int*)alloc(256);

  const int NB_SCAN = (N_NODES + 255) / 256;  // 391

  hipMemsetAsync(deg, 0, (size_t)N_NODES * 4, stream);
  k_detect<<<1, 64, 0, stream>>>(ei, flag);
  k_prep<<<(131136 + 255) / 256, 256, 0, stream>>>(W, proj_w, W_edge, att, Bt, Pt, w3);
  k_gemm_x<<<(N_NODES + 63) / 64, 256, 0, stream>>>(x, Bt, att, xwb, s1, s2);
  k_deg<<<(E_EDGES + 255) / 256, 256, 0, stream>>>(ei, flag, deg);
  k_scan1<<<NB_SCAN, 256, 0, stream>>>(deg, rowptr, bsum);
  k_scan2<<<1, 512, 0, stream>>>(bsum, NB_SCAN);
  k_scan3<<<NB_SCAN, 256, 0, stream>>>(rowptr, bsum, cursor);
  k_edge<<<(E_EDGES + 255) / 256, 256, 0, stream>>>(ei, flag, edge_attr, s1, s2, w3,
                                                    cursor, src_csr, expb);
  k_aggr<<<(N_NODES + 3) / 4, 256, 0, stream>>>(rowptr, src_csr, expb, xwb, outhb);
  k_gemm_out<<<(N_NODES + 63) / 64, 256, 0, stream>>>(outhb, Pt, proj_b, out);
}

// Round 3
// 471.119 us; speedup vs baseline: 1.2883x; 1.1680x over previous
//
#include <hip/hip_runtime.h>
#include <hip/hip_bf16.h>
#include <stdint.h>

#define N_NODES 100000
#define E_EDGES 1600000
#define NEG_SLOPE 0.2f

typedef short short8 __attribute__((ext_vector_type(8)));
typedef float f32x4 __attribute__((ext_vector_type(4)));

__device__ __forceinline__ unsigned short f2bf(float f) {
  union { float f; unsigned int u; } c; c.f = f;
  unsigned int u = c.u;
  unsigned int r = u + 0x7FFFu + ((u >> 16) & 1u);
  return (unsigned short)(r >> 16);
}
__device__ __forceinline__ float asf(unsigned int u) {
  union { unsigned int u; float f; } c; c.u = u;
  return c.f;
}
__device__ __forceinline__ float bf2f(unsigned short b) { return asf(((unsigned int)b) << 16); }

// ---- detect int32 vs int64 edge_index: int64 => odd int32 words are all 0
__global__ void k_detect(const void* ei, int* flag) {
  int t = threadIdx.x;
  int v = ((const int*)ei)[2 * t + 1];
  unsigned long long b = __ballot(v != 0);
  if (t == 0) *flag = (b != 0ull) ? 1 : 0;  // 1 = int32 layout
}

// ---- pack W -> Bt[col][k] bf16, proj_w -> Pt[col][k] bf16, w3[h][d] = sum_o W_edge[h][d][o]*a3[h][o]
__global__ void k_prep(const float* __restrict__ W, const float* __restrict__ proj_w,
                       const float* __restrict__ W_edge, const float* __restrict__ att,
                       unsigned short* __restrict__ Bt, unsigned short* __restrict__ Pt,
                       float* __restrict__ w3) {
  int t = blockIdx.x * 256 + threadIdx.x;
  if (t < 65536) {
    int col = t >> 8, k = t & 255;
    int h = col >> 6, o = col & 63;
    Bt[t] = f2bf(W[h * 16384 + k * 64 + o]);
  } else if (t < 131072) {
    int t2 = t - 65536;
    int o = t2 >> 8, i = t2 & 255;
    Pt[t2] = f2bf(proj_w[i * 256 + o]);
  } else if (t < 131136) {
    int t3 = t - 131072;
    int h = t3 >> 4, d = t3 & 15;
    float s = 0.f;
    for (int o = 0; o < 64; ++o)
      s += W_edge[h * 1024 + d * 64 + o] * att[h * 192 + 128 + o];
    w3[t3] = s;
  }
}

// ---- GEMM: xwb[n][h*64+o] = bf16( sum_k x[n][k] * Bt[h*64+o][k] )
//      A-tile staged in LDS (bf16, XOR-swizzled granules: P = G ^ (row&7))
//      fused epilogue: s1[n][h], s2[n][h]  (wave w == head w)
__global__ __launch_bounds__(256, 4) void k_gemm_x(const float* __restrict__ x,
    const unsigned short* __restrict__ Bt, const float* __restrict__ att,
    unsigned short* __restrict__ xwb, float* __restrict__ s1, float* __restrict__ s2) {
  __shared__ unsigned short As[16384];  // [64 rows][256 k] bf16, swizzled, 32KB
  const int bm = blockIdx.x * 64;
  const int t = threadIdx.x;

  // stage: fp32 -> bf16, coalesced float4 reads, swizzled ds_write_b64
#pragma unroll
  for (int i = 0; i < 16; ++i) {
    int c = i * 256 + t;
    int row = c >> 6, f4 = c & 63;  // f4 = float4-chunk within row (k = f4*4..+3)
    uint2 w = make_uint2(0u, 0u);
    if (bm + row < N_NODES) {
      float4 v = *(const float4*)(x + (size_t)(bm + row) * 256 + f4 * 4);
      w.x = (unsigned int)f2bf(v.x) | ((unsigned int)f2bf(v.y) << 16);
      w.y = (unsigned int)f2bf(v.z) | ((unsigned int)f2bf(v.w) << 16);
    }
    int phys = row * 512 + (((f4 >> 1) ^ (row & 7)) << 4) + ((f4 & 1) << 3);
    *(uint2*)((char*)As + phys) = w;
  }
  __syncthreads();

  const int wave = t >> 6;
  const int lane = t & 63;
  const int l16 = lane & 15, lg = lane >> 4;
  const int colbase = wave * 64;
  f32x4 acc[4][4];
#pragma unroll
  for (int i = 0; i < 4; i++)
#pragma unroll
    for (int j = 0; j < 4; j++) acc[i][j] = (f32x4){0.f, 0.f, 0.f, 0.f};

  for (int ks = 0; ks < 8; ++ks) {
    const int k0 = ks * 32 + lg * 8;
    short8 a[4], b[4];
#pragma unroll
    for (int mi = 0; mi < 4; mi++) {
      int row = mi * 16 + l16;
      int phys = row * 512 + (((ks * 4 + lg) ^ (row & 7)) << 4);
      a[mi] = *(const short8*)((const char*)As + phys);
    }
#pragma unroll
    for (int ni = 0; ni < 4; ni++) {
      int col = colbase + ni * 16 + l16;
      b[ni] = *(const short8*)(Bt + col * 256 + k0);
    }
#pragma unroll
    for (int mi = 0; mi < 4; mi++)
#pragma unroll
      for (int ni = 0; ni < 4; ni++)
        acc[mi][ni] = __builtin_amdgcn_mfma_f32_16x16x32_bf16(a[mi], b[ni], acc[mi][ni], 0, 0, 0);
  }

  // epilogue: store xwb + fused per-row attention scores for this wave's head
  float a1v[4], a2v[4];
#pragma unroll
  for (int ni = 0; ni < 4; ni++) {
    a1v[ni] = att[wave * 192 + ni * 16 + l16];
    a2v[ni] = att[wave * 192 + 64 + ni * 16 + l16];
  }
#pragma unroll
  for (int mi = 0; mi < 4; mi++) {
#pragma unroll
    for (int r = 0; r < 4; r++) {
      int row = bm + mi * 16 + lg * 4 + r;
      float p1 = 0.f, p2 = 0.f;
#pragma unroll
      for (int ni = 0; ni < 4; ni++) {
        float v = acc[mi][ni][r];
        p1 += v * a1v[ni];
        p2 += v * a2v[ni];
      }
#pragma unroll
      for (int m = 1; m < 16; m <<= 1) {
        p1 += __shfl_xor(p1, m, 64);
        p2 += __shfl_xor(p2, m, 64);
      }
      if (row < N_NODES) {
#pragma unroll
        for (int ni = 0; ni < 4; ni++) {
          int col = colbase + ni * 16 + l16;
          xwb[(size_t)row * 256 + col] = f2bf(acc[mi][ni][r]);
        }
        if (l16 == 0) {
          s1[row * 4 + wave] = p1;
          s2[row * 4 + wave] = p2;
        }
      }
    }
  }
}

__global__ void k_deg(const void* ei, const int* __restrict__ flag, int* __restrict__ deg) {
  int e = blockIdx.x * 256 + threadIdx.x;
  if (e >= E_EDGES) return;
  int f = *flag;
  int dst = f ? ((const int*)ei)[E_EDGES + e] : (int)(((const long long*)ei)[E_EDGES + e]);
  atomicAdd(&deg[dst], 1);
}

__global__ void k_scan1(const int* __restrict__ deg, int* __restrict__ rowptr, int* __restrict__ bsum) {
  __shared__ int s[256];
  int t = threadIdx.x;
  int i = blockIdx.x * 256 + t;
  int orig = (i < N_NODES) ? deg[i] : 0;
  int v = orig;
  s[t] = v;
  __syncthreads();
  for (int off = 1; off < 256; off <<= 1) {
    int x = (t >= off) ? s[t - off] : 0;
    __syncthreads();
    v += x;
    s[t] = v;
    __syncthreads();
  }
  if (i < N_NODES) rowptr[i] = v - orig;  // block-local exclusive
  if (t == 255) bsum[blockIdx.x] = v;     // block total
}

__global__ void k_scan2(int* __restrict__ bsum, int nb) {
  __shared__ int s[512];
  int t = threadIdx.x;
  int v = (t < nb) ? bsum[t] : 0;
  int incl = v;
  s[t] = v;
  __syncthreads();
  for (int off = 1; off < 512; off <<= 1) {
    int x = (t >= off) ? s[t - off] : 0;
    __syncthreads();
    incl += x;
    s[t] = incl;
    __syncthreads();
  }
  if (t < nb) bsum[t] = incl - v;  // exclusive
}

__global__ void k_scan3(int* __restrict__ rowptr, const int* __restrict__ bsum, int* __restrict__ cursor) {
  int i = blockIdx.x * 256 + threadIdx.x;
  if (i < N_NODES) {
    int v = rowptr[i] + bsum[i >> 8];
    rowptr[i] = v;
    cursor[i] = v;
  }
  if (i == 0) rowptr[N_NODES] = E_EDGES;
}

// ---- per-edge: e-vals (4 heads), leakyrelu, exp (softmax is shift-invariant -> no max pass),
//      scatter (src, exp packed bf16) into CSR slot
__global__ void k_edge(const void* ei, const int* __restrict__ flag,
                       const float* __restrict__ edge_attr,
                       const float* __restrict__ s1, const float* __restrict__ s2,
                       const float* __restrict__ w3g, int* __restrict__ cursor,
                       int* __restrict__ src_csr, uint2* __restrict__ expb) {
  __shared__ float w3[64];
  if (threadIdx.x < 64) w3[threadIdx.x] = w3g[threadIdx.x];
  __syncthreads();
  int e = blockIdx.x * 256 + threadIdx.x;
  if (e >= E_EDGES) return;
  int f = *flag;
  int src, dst;
  if (f) {
    src = ((const int*)ei)[e];
    dst = ((const int*)ei)[E_EDGES + e];
  } else {
    src = (int)(((const long long*)ei)[e]);
    dst = (int)(((const long long*)ei)[E_EDGES + e]);
  }
  float4 sd = *(const float4*)(s1 + (size_t)dst * 4);
  float4 ss = *(const float4*)(s2 + (size_t)src * 4);
  float ea[16];
#pragma unroll
  for (int i = 0; i < 4; i++) {
    float4 v = *(const float4*)(edge_attr + (size_t)e * 16 + i * 4);
    ea[4 * i] = v.x; ea[4 * i + 1] = v.y; ea[4 * i + 2] = v.z; ea[4 * i + 3] = v.w;
  }
  float ex[4];
#pragma unroll
  for (int h = 0; h < 4; h++) {
    float d = 0.f;
#pragma unroll
    for (int i = 0; i < 16; i++) d += ea[i] * w3[h * 16 + i];
    float v = (&sd.x)[h] + (&ss.x)[h] + d;
    v = (v >= 0.f) ? v : NEG_SLOPE * v;
    ex[h] = __expf(v);
  }
  unsigned int p0 = ((unsigned int)f2bf(ex[1]) << 16) | (unsigned int)f2bf(ex[0]);
  unsigned int p1 = ((unsigned int)f2bf(ex[3]) << 16) | (unsigned int)f2bf(ex[2]);
  int p = atomicAdd(&cursor[dst], 1);
  src_csr[p] = src;
  expb[p] = make_uint2(p0, p1);
}

// ---- one wave per node: out_h[n][c] = (1/den) * sum_edges exp * xw[src][c]; write bf16
//      unroll x4: 8 outstanding gathers, src hoisted to SGPR (wave-uniform)
__global__ __launch_bounds__(256) void k_aggr(const int* __restrict__ rowptr,
    const int* __restrict__ src_csr, const uint2* __restrict__ expb,
    const unsigned short* __restrict__ xwb, unsigned short* __restrict__ out_hb) {
  int n = blockIdx.x * 4 + (threadIdx.x >> 6);
  if (n >= N_NODES) return;
  int lane = threadIdx.x & 63;
  int beg = rowptr[n], end = rowptr[n + 1];
  const int cA = 2 * lane;  // dims cA, cA+1 (A-half: heads 0/1), +128: B-half (heads 2/3)
  const bool lo32 = (lane < 32);
  float accA0 = 0.f, accA1 = 0.f, accB0 = 0.f, accB1 = 0.f;
  float den0 = 0.f, den1 = 0.f, den2 = 0.f, den3 = 0.f;

#define EDGE_FMA(eu, uA, uB)                                              \
  {                                                                       \
    float d0 = asf(eu.x << 16), d1 = asf(eu.x & 0xFFFF0000u);             \
    float d2 = asf(eu.y << 16), d3 = asf(eu.y & 0xFFFF0000u);             \
    den0 += d0; den1 += d1; den2 += d2; den3 += d3;                       \
    float wAB = lo32 ? d0 : d1;                                           \
    float wCD = lo32 ? d2 : d3;                                           \
    accA0 += wAB * asf(uA << 16); accA1 += wAB * asf(uA & 0xFFFF0000u);   \
    accB0 += wCD * asf(uB << 16); accB1 += wCD * asf(uB & 0xFFFF0000u);   \
  }

  int i = beg;
  for (; i + 4 <= end; i += 4) {
    int s0 = __builtin_amdgcn_readfirstlane(src_csr[i]);
    int s1_ = __builtin_amdgcn_readfirstlane(src_csr[i + 1]);
    int s2_ = __builtin_amdgcn_readfirstlane(src_csr[i + 2]);
    int s3_ = __builtin_amdgcn_readfirstlane(src_csr[i + 3]);
    uint2 e0 = expb[i], e1 = expb[i + 1], e2 = expb[i + 2], e3 = expb[i + 3];
    const unsigned short* r0 = xwb + (size_t)s0 * 256;
    const unsigned short* r1 = xwb + (size_t)s1_ * 256;
    const unsigned short* r2 = xwb + (size_t)s2_ * 256;
    const unsigned short* r3 = xwb + (size_t)s3_ * 256;
    unsigned int uA0 = *(const unsigned int*)(r0 + cA);
    unsigned int uB0 = *(const unsigned int*)(r0 + cA + 128);
    unsigned int uA1 = *(const unsigned int*)(r1 + cA);
    unsigned int uB1 = *(const unsigned int*)(r1 + cA + 128);
    unsigned int uA2 = *(const unsigned int*)(r2 + cA);
    unsigned int uB2 = *(const unsigned int*)(r2 + cA + 128);
    unsigned int uA3 = *(const unsigned int*)(r3 + cA);
    unsigned int uB3 = *(const unsigned int*)(r3 + cA + 128);
    EDGE_FMA(e0, uA0, uB0);
    EDGE_FMA(e1, uA1, uB1);
    EDGE_FMA(e2, uA2, uB2);
    EDGE_FMA(e3, uA3, uB3);
  }
  for (; i < end; ++i) {
    int s0 = __builtin_amdgcn_readfirstlane(src_csr[i]);
    uint2 e0 = expb[i];
    const unsigned short* r0 = xwb + (size_t)s0 * 256;
    unsigned int uA0 = *(const unsigned int*)(r0 + cA);
    unsigned int uB0 = *(const unsigned int*)(r0 + cA + 128);
    EDGE_FMA(e0, uA0, uB0);
  }
#undef EDGE_FMA

  float dA = (lo32 ? den0 : den1) + 1e-16f;
  float dB = (lo32 ? den2 : den3) + 1e-16f;
  unsigned int oA = ((unsigned int)f2bf(accA1 / dA) << 16) | (unsigned int)f2bf(accA0 / dA);
  unsigned int oB = ((unsigned int)f2bf(accB1 / dB) << 16) | (unsigned int)f2bf(accB0 / dB);
  *(unsigned int*)(out_hb + (size_t)n * 256 + cA) = oA;
  *(unsigned int*)(out_hb + (size_t)n * 256 + cA + 128) = oB;
}

// ---- out = elu(out_hb @ Pt^T + bias), A-tile staged in LDS (same swizzle)
__global__ __launch_bounds__(256, 4) void k_gemm_out(const unsigned short* __restrict__ A,
    const unsigned short* __restrict__ Pt, const float* __restrict__ bias,
    float* __restrict__ out) {
  __shared__ unsigned short As[16384];  // [64][256] bf16 swizzled
  const int bm = blockIdx.x * 64;
  const int t = threadIdx.x;

#pragma unroll
  for (int i = 0; i < 8; ++i) {
    int c = i * 256 + t;
    int row = c >> 5, G = c & 31;  // G = 16B-granule (8 bf16) within row
    short8 v = (short8){0, 0, 0, 0, 0, 0, 0, 0};
    if (bm + row < N_NODES) v = *(const short8*)(A + (size_t)(bm + row) * 256 + G * 8);
    int phys = row * 512 + ((G ^ (row & 7)) << 4);
    *(short8*)((char*)As + phys) = v;
  }
  __syncthreads();

  const int wave = t >> 6;
  const int lane = t & 63;
  const int l16 = lane & 15, lg = lane >> 4;
  const int colbase = wave * 64;
  f32x4 acc[4][4];
#pragma unroll
  for (int i = 0; i < 4; i++)
#pragma unroll
    for (int j = 0; j < 4; j++) acc[i][j] = (f32x4){0.f, 0.f, 0.f, 0.f};

  for (int ks = 0; ks < 8; ++ks) {
    const int k0 = ks * 32 + lg * 8;
    short8 a[4], b[4];
#pragma unroll
    for (int mi = 0; mi < 4; mi++) {
      int row = mi * 16 + l16;
      int phys = row * 512 + (((ks * 4 + lg) ^ (row & 7)) << 4);
      a[mi] = *(const short8*)((const char*)As + phys);
    }
#pragma unroll
    for (int ni = 0; ni < 4; ni++) {
      int col = colbase + ni * 16 + l16;
      b[ni] = *(const short8*)(Pt + col * 256 + k0);
    }
#pragma unroll
    for (int mi = 0; mi < 4; mi++)
#pragma unroll
      for (int ni = 0; ni < 4; ni++)
        acc[mi][ni] = __builtin_amdgcn_mfma_f32_16x16x32_bf16(a[mi], b[ni], acc[mi][ni], 0, 0, 0);
  }
#pragma unroll
  for (int mi = 0; mi < 4; mi++) {
#pragma unroll
    for (int r = 0; r < 4; r++) {
      int row = bm + mi * 16 + lg * 4 + r;
      if (row < N_NODES) {
#pragma unroll
        for (int ni = 0; ni < 4; ni++) {
          int col = colbase + ni * 16 + l16;
          float v = acc[mi][ni][r] + bias[col];
          v = (v > 0.f) ? v : expm1f(v);
          out[(size_t)row * 256 + col] = v;
        }
      }
    }
  }
}

extern "C" void kernel_launch(void* const* d_in, const int* in_sizes, int n_in,
                              void* d_out, int out_size, void* d_ws, size_t ws_size,
                              hipStream_t stream) {
  const float* x = (const float*)d_in[0];
  const void* ei = d_in[1];
  const float* edge_attr = (const float*)d_in[2];
  const float* W = (const float*)d_in[3];
  const float* W_edge = (const float*)d_in[4];
  const float* att = (const float*)d_in[5];
  const float* proj_w = (const float*)d_in[6];
  const float* proj_b = (const float*)d_in[7];
  float* out = (float*)d_out;

  char* ws = (char*)d_ws;
  size_t off = 0;
  auto alloc = [&](size_t bytes) -> void* {
    void* p = (void*)(ws + off);
    off += (bytes + 255) & ~(size_t)255;
    return p;
  };
  unsigned short* xwb   = (unsigned short*)alloc((size_t)N_NODES * 256 * 2);
  unsigned short* outhb = (unsigned short*)alloc((size_t)N_NODES * 256 * 2);
  float* s1      = (float*)alloc((size_t)N_NODES * 4 * 4);
  float* s2      = (float*)alloc((size_t)N_NODES * 4 * 4);
  int* deg       = (int*)alloc((size_t)N_NODES * 4);
  int* rowptr    = (int*)alloc((size_t)(N_NODES + 1) * 4);
  int* cursor    = (int*)alloc((size_t)N_NODES * 4);
  int* bsum      = (int*)alloc(512 * 4);
  int* src_csr   = (int*)alloc((size_t)E_EDGES * 4);
  uint2* expb    = (uint2*)alloc((size_t)E_EDGES * 8);
  unsigned short* Bt = (unsigned short*)alloc(65536 * 2);
  unsigned short* Pt = (unsigned short*)alloc(65536 * 2);
  float* w3      = (float*)alloc(64 * 4);
  int* flag      = (int*)alloc(256);

  const int NB_SCAN = (N_NODES + 255) / 256;  // 391

  hipMemsetAsync(deg, 0, (size_t)N_NODES * 4, stream);
  k_detect<<<1, 64, 0, stream>>>(ei, flag);
  k_prep<<<(131136 + 255) / 256, 256, 0, stream>>>(W, proj_w, W_edge, att, Bt, Pt, w3);
  k_gemm_x<<<(N_NODES + 63) / 64, 256, 0, stream>>>(x, Bt, att, xwb, s1, s2);
  k_deg<<<(E_EDGES + 255) / 256, 256, 0, stream>>>(ei, flag, deg);
  k_scan1<<<NB_SCAN, 256, 0, stream>>>(deg, rowptr, bsum);
  k_scan2<<<1, 512, 0, stream>>>(bsum, NB_SCAN);
  k_scan3<<<NB_SCAN, 256, 0, stream>>>(rowptr, bsum, cursor);
  k_edge<<<(E_EDGES + 255) / 256, 256, 0, stream>>>(ei, flag, edge_attr, s1, s2, w3,
                                                    cursor, src_csr, expb);
  k_aggr<<<(N_NODES + 3) / 4, 256, 0, stream>>>(rowptr, src_csr, expb, xwb, outhb);
  k_gemm_out<<<(N_NODES + 63) / 64, 256, 0, stream>>>(outhb, Pt, proj_b, out);
}